// Round 2
// baseline (211.904 us; speedup 1.0000x reference)
//
#include <hip/hip_runtime.h>
#include <math.h>

#define THREADS 256
#define INV_SQRT2 0.70710678118654752440f

// ---- monotonic float<->uint key transform (ascending order preserved) ----
__device__ __forceinline__ unsigned f2key(float f) {
    unsigned u = __float_as_uint(f);
    return (u & 0x80000000u) ? ~u : (u | 0x80000000u);
}
__device__ __forceinline__ float key2f(unsigned k) {
    unsigned u = (k & 0x80000000u) ? (k & 0x7fffffffu) : ~k;
    return __uint_as_float(u);
}

__device__ __forceinline__ float gelu_erf(float v) {
    return 0.5f * v * (1.0f + erff(v * INV_SQRT2));
}

// One-block-cooperative selection over 256*chunk cumulative histogram bins.
// All threads return the same (bucket, krem). Requires blockDim.x == 256.
__device__ void block_select(const unsigned* __restrict__ hist, int chunk,
                             long long kin, unsigned* bucket_out, long long* krem_out) {
    __shared__ unsigned s_ps[256];
    __shared__ unsigned s_bucket;
    __shared__ unsigned s_krem;
    const int t = threadIdx.x;
    const unsigned* h = hist + (size_t)t * chunk;
    unsigned s = 0;
    for (int i = 0; i < chunk; ++i) s += h[i];
    s_ps[t] = s;
    __syncthreads();
    if (t == 0) {
        unsigned run = 0;
        for (int i = 0; i < 256; ++i) { unsigned c = s_ps[i]; s_ps[i] = run; run += c; }
    }
    __syncthreads();
    long long base = (long long)s_ps[t];
    for (int i = 0; i < chunk; ++i) {
        unsigned c = h[i];
        if (base < kin && kin <= base + (long long)c) {
            s_bucket = (unsigned)(t * chunk + i);
            s_krem = (unsigned)(kin - base);
        }
        base += (long long)c;
    }
    __syncthreads();
    *bucket_out = s_bucket;
    *krem_out = (long long)s_krem;
    __syncthreads();
}

// ======================= FAST PATH (2 full passes) =========================

// K1: fused GELU + 12-bit first-level histogram (key bits 31:20).
__global__ void __launch_bounds__(THREADS) k_gelu_hist12(
    const float4* __restrict__ x, float4* __restrict__ out,
    unsigned* __restrict__ h12, long long n4)
{
    __shared__ unsigned lh[4096 * 2];  // 2 sub-copies, interleaved
    for (int i = threadIdx.x; i < 4096 * 2; i += THREADS) lh[i] = 0;
    __syncthreads();
    const int c = threadIdx.x & 1;
    const long long stride = (long long)gridDim.x * THREADS;
    for (long long i = (long long)blockIdx.x * THREADS + threadIdx.x; i < n4; i += stride) {
        float4 v = x[i];
        float4 g;
        g.x = gelu_erf(v.x);
        g.y = gelu_erf(v.y);
        g.z = gelu_erf(v.z);
        g.w = gelu_erf(v.w);
        out[i] = g;
        atomicAdd(&lh[((f2key(v.x) >> 20) << 1) + c], 1u);
        atomicAdd(&lh[((f2key(v.y) >> 20) << 1) + c], 1u);
        atomicAdd(&lh[((f2key(v.z) >> 20) << 1) + c], 1u);
        atomicAdd(&lh[((f2key(v.w) >> 20) << 1) + c], 1u);
    }
    __syncthreads();
    for (int b = threadIdx.x; b < 4096; b += THREADS) {
        unsigned s = lh[2 * b] + lh[2 * b + 1];
        if (s) atomicAdd(&h12[b], s);
    }
}

#define CBUF 4096

// K2: tentative x_saved for all elements, compact level-1-bucket candidates
// (value+index) to global, and build level-2 histogram (key bits 19:8) of them.
__global__ void __launch_bounds__(THREADS) k_saved_compact(
    const float4* __restrict__ x, float4* __restrict__ outs,
    const unsigned* __restrict__ h12, unsigned* __restrict__ h12b,
    float* __restrict__ cval, unsigned* __restrict__ cidx,
    unsigned* __restrict__ ccnt, unsigned cap, long long k0, long long n4)
{
    __shared__ unsigned lh[4096];
    __shared__ float sv[CBUF];
    __shared__ unsigned si[CBUF];
    __shared__ unsigned s_cnt, s_n, s_base;
    unsigned b1; long long k1;
    block_select(h12, 16, k0, &b1, &k1);
    for (int i = threadIdx.x; i < 4096; i += THREADS) lh[i] = 0;
    if (threadIdx.x == 0) s_cnt = 0;
    __syncthreads();
    const long long stride = (long long)gridDim.x * THREADS;
    for (long long i = (long long)blockIdx.x * THREADS + threadIdx.x; i < n4; i += stride) {
        float4 v = x[i];
        float4 r;
        const float* vp = (const float*)&v;
        float* rp = (float*)&r;
        #pragma unroll
        for (int c = 0; c < 4; ++c) {
            float val = vp[c];
            unsigned k = f2key(val);
            unsigned pre = k >> 20;
            if (pre == b1) {
                unsigned pos = atomicAdd(&s_cnt, 1u);
                if (pos < CBUF) { sv[pos] = val; si[pos] = (unsigned)(i * 4 + c); }
                atomicAdd(&lh[(k >> 8) & 0xFFFu], 1u);
                rp[c] = -10.0f;          // fixed up in K4
            } else {
                rp[c] = (pre > b1) ? val : -10.0f;
            }
        }
        outs[i] = r;
    }
    __syncthreads();
    for (int b = threadIdx.x; b < 4096; b += THREADS) {
        unsigned s = lh[b];
        if (s) atomicAdd(&h12b[b], s);
    }
    if (threadIdx.x == 0) {
        unsigned cnt = s_cnt < CBUF ? s_cnt : CBUF;
        s_n = cnt;
        s_base = atomicAdd(ccnt, cnt);
    }
    __syncthreads();
    const unsigned base = s_base, nn = s_n;
    for (unsigned j = threadIdx.x; j < nn; j += THREADS) {
        unsigned d = base + j;
        if (d < cap) { cval[d] = sv[j]; cidx[d] = si[j]; }
    }
}

// K3: level-3 histogram (key bits 7:0) of candidates matching level-2 bucket.
__global__ void __launch_bounds__(THREADS) k_hist8c(
    const float* __restrict__ cval, const unsigned* __restrict__ ccnt, unsigned cap,
    const unsigned* __restrict__ h12, const unsigned* __restrict__ h12b,
    unsigned* __restrict__ h8c, long long k0)
{
    __shared__ unsigned lh[256];
    unsigned b1, b2; long long k1, k2;
    block_select(h12, 16, k0, &b1, &k1);
    block_select(h12b, 16, k1, &b2, &k2);
    lh[threadIdx.x] = 0;
    __syncthreads();
    unsigned n = *ccnt; if (n > cap) n = cap;
    const unsigned stride = gridDim.x * THREADS;
    for (unsigned j = blockIdx.x * THREADS + threadIdx.x; j < n; j += stride) {
        unsigned k = f2key(cval[j]);
        if (((k >> 8) & 0xFFFu) == b2) atomicAdd(&lh[k & 0xFFu], 1u);
    }
    __syncthreads();
    unsigned s = lh[threadIdx.x];
    if (s) atomicAdd(&h8c[threadIdx.x], s);
}

// K4: derive exact kth, write scalar, fix up candidate positions of x_saved.
__global__ void __launch_bounds__(THREADS) k_finalize(
    const float* __restrict__ cval, const unsigned* __restrict__ cidx,
    const unsigned* __restrict__ ccnt, unsigned cap,
    float* __restrict__ outs_scalar, float* __restrict__ kth_out,
    const unsigned* __restrict__ h12, const unsigned* __restrict__ h12b,
    const unsigned* __restrict__ h8c, long long k0)
{
    unsigned b1, b2, b3; long long k1, k2, k3;
    block_select(h12, 16, k0, &b1, &k1);
    block_select(h12b, 16, k1, &b2, &k2);
    block_select(h8c, 1, k2, &b3, &k3);
    const unsigned kthkey = (b1 << 20) | (b2 << 8) | b3;
    const float kth = key2f(kthkey);
    if (blockIdx.x == 0 && threadIdx.x == 0) *kth_out = kth;
    unsigned n = *ccnt; if (n > cap) n = cap;
    const unsigned stride = gridDim.x * THREADS;
    for (unsigned j = blockIdx.x * THREADS + threadIdx.x; j < n; j += stride) {
        float v = cval[j];
        unsigned k = f2key(v);
        outs_scalar[cidx[j]] = (k > kthkey) ? v : -10.0f;
    }
}

// ======================= FALLBACK PATH (R1, proven) ========================

__global__ void __launch_bounds__(THREADS) k_gelu_hist8(
    const float4* __restrict__ x, float4* __restrict__ out,
    unsigned* __restrict__ hist8, long long n4)
{
    __shared__ unsigned lh[256 * 4];
    for (int i = threadIdx.x; i < 256 * 4; i += THREADS) lh[i] = 0;
    __syncthreads();
    const int c = threadIdx.x & 3;
    const long long stride = (long long)gridDim.x * THREADS;
    for (long long i = (long long)blockIdx.x * THREADS + threadIdx.x; i < n4; i += stride) {
        float4 v = x[i];
        float4 g;
        g.x = gelu_erf(v.x);
        g.y = gelu_erf(v.y);
        g.z = gelu_erf(v.z);
        g.w = gelu_erf(v.w);
        out[i] = g;
        atomicAdd(&lh[((f2key(v.x) >> 24) << 2) + c], 1u);
        atomicAdd(&lh[((f2key(v.y) >> 24) << 2) + c], 1u);
        atomicAdd(&lh[((f2key(v.z) >> 24) << 2) + c], 1u);
        atomicAdd(&lh[((f2key(v.w) >> 24) << 2) + c], 1u);
    }
    __syncthreads();
    const int t = threadIdx.x;
    unsigned s = lh[t * 4] + lh[t * 4 + 1] + lh[t * 4 + 2] + lh[t * 4 + 3];
    if (s) atomicAdd(&hist8[t], s);
}

__global__ void __launch_bounds__(THREADS) k_hist12(
    const float4* __restrict__ x, long long n4, long long k0,
    const unsigned* __restrict__ h8, const unsigned* __restrict__ h12a,
    unsigned* __restrict__ hist_out, int stage)
{
    __shared__ unsigned lh[4096];
    unsigned b1; long long k1;
    block_select(h8, 1, k0, &b1, &k1);
    unsigned matchval = b1;
    int matchshift = 24;
    if (stage == 1) {
        unsigned b2; long long k2;
        block_select(h12a, 16, k1, &b2, &k2);
        matchval = (b1 << 12) | b2;
        matchshift = 12;
    }
    for (int i = threadIdx.x; i < 4096; i += THREADS) lh[i] = 0;
    __syncthreads();
    const int binshift = matchshift - 12;
    const long long stride = (long long)gridDim.x * THREADS;
    for (long long i = (long long)blockIdx.x * THREADS + threadIdx.x; i < n4; i += stride) {
        float4 v = x[i];
        unsigned k;
        k = f2key(v.x); if ((k >> matchshift) == matchval) atomicAdd(&lh[(k >> binshift) & 0xFFFu], 1u);
        k = f2key(v.y); if ((k >> matchshift) == matchval) atomicAdd(&lh[(k >> binshift) & 0xFFFu], 1u);
        k = f2key(v.z); if ((k >> matchshift) == matchval) atomicAdd(&lh[(k >> binshift) & 0xFFFu], 1u);
        k = f2key(v.w); if ((k >> matchshift) == matchval) atomicAdd(&lh[(k >> binshift) & 0xFFFu], 1u);
    }
    __syncthreads();
    for (int i = threadIdx.x; i < 4096; i += THREADS) {
        unsigned s = lh[i];
        if (s) atomicAdd(&hist_out[i], s);
    }
}

__global__ void __launch_bounds__(THREADS) k_xsaved(
    const float4* __restrict__ x, float4* __restrict__ out, float* __restrict__ kth_out,
    const unsigned* __restrict__ h8, const unsigned* __restrict__ h12a,
    const unsigned* __restrict__ h12b, long long k0, long long n4)
{
    unsigned b1, b2, b3; long long k1, k2, k3;
    block_select(h8, 1, k0, &b1, &k1);
    block_select(h12a, 16, k1, &b2, &k2);
    block_select(h12b, 16, k2, &b3, &k3);
    const unsigned key = (b1 << 24) | (b2 << 12) | b3;
    const float kth = key2f(key);
    if (blockIdx.x == 0 && threadIdx.x == 0) *kth_out = kth;
    const long long stride = (long long)gridDim.x * THREADS;
    for (long long i = (long long)blockIdx.x * THREADS + threadIdx.x; i < n4; i += stride) {
        float4 v = x[i];
        float4 r;
        r.x = v.x > kth ? v.x : -10.0f;
        r.y = v.y > kth ? v.y : -10.0f;
        r.z = v.z > kth ? v.z : -10.0f;
        r.w = v.w > kth ? v.w : -10.0f;
        out[i] = r;
    }
}

// ===========================================================================

extern "C" void kernel_launch(void* const* d_in, const int* in_sizes, int n_in,
                              void* d_out, int out_size, void* d_ws, size_t ws_size,
                              hipStream_t stream) {
    (void)n_in; (void)out_size;
    const float* x = (const float*)d_in[0];
    float* out = (float*)d_out;
    const long long n = (long long)in_sizes[0];         // 33,554,432
    const long long n4 = n / 4;
    const long long k0 = (long long)((double)n * 0.9);  // matches Python int(n*0.9)

    float* gelu_out   = out;            // [0, n)
    float* xsaved_out = out + n;        // [n, 2n)
    float* kth_out    = out + 2 * n;    // [2n]

    // ws layout (fast path): h12[4096] | h12b[4096] | h8c[256] | cnt[1] | pad
    // then cval[cap] floats + cidx[cap] uints.
    const size_t HDR_U32 = 4096 + 4096 + 256 + 64;      // padded header
    const size_t hdr_bytes = HDR_U32 * sizeof(unsigned);

    if (ws_size >= hdr_bytes + (size_t)16 * 1024 * 1024) {
        unsigned* h12  = (unsigned*)d_ws;
        unsigned* h12b = h12 + 4096;
        unsigned* h8c  = h12b + 4096;
        unsigned* ccnt = h8c + 256;
        unsigned cap = (unsigned)((ws_size - hdr_bytes) / 8);
        float*    cval = (float*)((char*)d_ws + hdr_bytes);
        unsigned* cidx = (unsigned*)(cval + cap);

        hipMemsetAsync(d_ws, 0, hdr_bytes, stream);
        k_gelu_hist12<<<1024, THREADS, 0, stream>>>((const float4*)x, (float4*)gelu_out, h12, n4);
        k_saved_compact<<<1024, THREADS, 0, stream>>>((const float4*)x, (float4*)xsaved_out,
                                                      h12, h12b, cval, cidx, ccnt, cap, k0, n4);
        k_hist8c<<<256, THREADS, 0, stream>>>(cval, ccnt, cap, h12, h12b, h8c, k0);
        k_finalize<<<256, THREADS, 0, stream>>>(cval, cidx, ccnt, cap, xsaved_out, kth_out,
                                                h12, h12b, h8c, k0);
    } else {
        // Fallback: proven R1 4-pass path (needs only ~34 KB of ws).
        unsigned* h8   = (unsigned*)d_ws;
        unsigned* h12a = h8 + 256;
        unsigned* h12b = h12a + 4096;
        hipMemsetAsync(d_ws, 0, (256 + 4096 + 4096) * sizeof(unsigned), stream);
        const int blocks = 2048;
        k_gelu_hist8<<<blocks, THREADS, 0, stream>>>((const float4*)x, (float4*)gelu_out, h8, n4);
        k_hist12<<<blocks, THREADS, 0, stream>>>((const float4*)x, n4, k0, h8, h12a, h12a, 0);
        k_hist12<<<blocks, THREADS, 0, stream>>>((const float4*)x, n4, k0, h8, h12a, h12b, 1);
        k_xsaved<<<blocks, THREADS, 0, stream>>>((const float4*)x, (float4*)xsaved_out, kth_out,
                                                 h8, h12a, h12b, k0, n4);
    }
}

// Round 4
// 178.150 us; speedup vs baseline: 1.1895x; 1.1895x over previous
//
#include <hip/hip_runtime.h>
#include <math.h>

#define THREADS 256
#define INV_SQRT2 0.70710678118654752440f

typedef float f32x4 __attribute__((ext_vector_type(4)));

__device__ __forceinline__ void nt_store4(const float4& v, float4* p) {
    f32x4 w = { v.x, v.y, v.z, v.w };
    __builtin_nontemporal_store(w, (f32x4*)p);
}

// ---- monotonic float<->uint key transform (ascending order preserved) ----
__device__ __forceinline__ unsigned f2key(float f) {
    unsigned u = __float_as_uint(f);
    return (u & 0x80000000u) ? ~u : (u | 0x80000000u);
}
__device__ __forceinline__ float key2f(unsigned k) {
    unsigned u = (k & 0x80000000u) ? (k & 0x7fffffffu) : ~k;
    return __uint_as_float(u);
}

__device__ __forceinline__ float gelu_erf(float v) {
    return 0.5f * v * (1.0f + erff(v * INV_SQRT2));
}

// Zero the ws header. Replaces hipMemsetAsync: the graph-captured memset node
// (fillBufferAligned) measured ~155 us/replay in R1/R2 rocprof — a plain
// kernel dispatch is ~2 us.
__global__ void __launch_bounds__(THREADS) k_zero(unsigned* __restrict__ p, int n) {
    int i = blockIdx.x * THREADS + threadIdx.x;
    if (i < n) p[i] = 0;
}

// One-block-cooperative selection over 256*chunk cumulative histogram bins.
// All threads return the same (bucket, krem). Requires blockDim.x == 256.
__device__ void block_select(const unsigned* __restrict__ hist, int chunk,
                             long long kin, unsigned* bucket_out, long long* krem_out) {
    __shared__ unsigned s_ps[256];
    __shared__ unsigned s_bucket;
    __shared__ unsigned s_krem;
    const int t = threadIdx.x;
    const unsigned* h = hist + (size_t)t * chunk;
    unsigned s = 0;
    for (int i = 0; i < chunk; ++i) s += h[i];
    s_ps[t] = s;
    __syncthreads();
    if (t == 0) {
        unsigned run = 0;
        for (int i = 0; i < 256; ++i) { unsigned c = s_ps[i]; s_ps[i] = run; run += c; }
    }
    __syncthreads();
    long long base = (long long)s_ps[t];
    for (int i = 0; i < chunk; ++i) {
        unsigned c = h[i];
        if (base < kin && kin <= base + (long long)c) {
            s_bucket = (unsigned)(t * chunk + i);
            s_krem = (unsigned)(kin - base);
        }
        base += (long long)c;
    }
    __syncthreads();
    *bucket_out = s_bucket;
    *krem_out = (long long)s_krem;
    __syncthreads();
}

// ======================= FAST PATH (2 full passes) =========================

// K1: fused GELU + 12-bit first-level histogram (key bits 31:20).
__global__ void __launch_bounds__(THREADS) k_gelu_hist12(
    const float4* __restrict__ x, float4* __restrict__ out,
    unsigned* __restrict__ h12, long long n4)
{
    __shared__ unsigned lh[4096 * 2];  // 2 sub-copies, interleaved
    for (int i = threadIdx.x; i < 4096 * 2; i += THREADS) lh[i] = 0;
    __syncthreads();
    const int c = threadIdx.x & 1;
    const long long stride = (long long)gridDim.x * THREADS;
    for (long long i = (long long)blockIdx.x * THREADS + threadIdx.x; i < n4; i += stride) {
        float4 v = x[i];
        float4 g;
        g.x = gelu_erf(v.x);
        g.y = gelu_erf(v.y);
        g.z = gelu_erf(v.z);
        g.w = gelu_erf(v.w);
        nt_store4(g, &out[i]);   // never re-read: keep x in L3
        atomicAdd(&lh[((f2key(v.x) >> 20) << 1) + c], 1u);
        atomicAdd(&lh[((f2key(v.y) >> 20) << 1) + c], 1u);
        atomicAdd(&lh[((f2key(v.z) >> 20) << 1) + c], 1u);
        atomicAdd(&lh[((f2key(v.w) >> 20) << 1) + c], 1u);
    }
    __syncthreads();
    for (int b = threadIdx.x; b < 4096; b += THREADS) {
        unsigned s = lh[2 * b] + lh[2 * b + 1];
        if (s) atomicAdd(&h12[b], s);
    }
}

#define CBUF 4096

// K2: tentative x_saved for all elements, compact level-1-bucket candidates
// (value+index) to global, and build level-2 histogram (key bits 19:8) of them.
__global__ void __launch_bounds__(THREADS) k_saved_compact(
    const float4* __restrict__ x, float4* __restrict__ outs,
    const unsigned* __restrict__ h12, unsigned* __restrict__ h12b,
    float* __restrict__ cval, unsigned* __restrict__ cidx,
    unsigned* __restrict__ ccnt, unsigned cap, long long k0, long long n4)
{
    __shared__ unsigned lh[4096];
    __shared__ float sv[CBUF];
    __shared__ unsigned si[CBUF];
    __shared__ unsigned s_cnt, s_n, s_base;
    unsigned b1; long long k1;
    block_select(h12, 16, k0, &b1, &k1);
    for (int i = threadIdx.x; i < 4096; i += THREADS) lh[i] = 0;
    if (threadIdx.x == 0) s_cnt = 0;
    __syncthreads();
    const long long stride = (long long)gridDim.x * THREADS;
    for (long long i = (long long)blockIdx.x * THREADS + threadIdx.x; i < n4; i += stride) {
        float4 v = x[i];
        float4 r;
        const float* vp = (const float*)&v;
        float* rp = (float*)&r;
        #pragma unroll
        for (int c = 0; c < 4; ++c) {
            float val = vp[c];
            unsigned k = f2key(val);
            unsigned pre = k >> 20;
            if (pre == b1) {
                unsigned pos = atomicAdd(&s_cnt, 1u);
                if (pos < CBUF) { sv[pos] = val; si[pos] = (unsigned)(i * 4 + c); }
                atomicAdd(&lh[(k >> 8) & 0xFFFu], 1u);
                rp[c] = -10.0f;          // fixed up in K4
            } else {
                rp[c] = (pre > b1) ? val : -10.0f;
            }
        }
        nt_store4(r, &outs[i]);
    }
    __syncthreads();
    for (int b = threadIdx.x; b < 4096; b += THREADS) {
        unsigned s = lh[b];
        if (s) atomicAdd(&h12b[b], s);
    }
    if (threadIdx.x == 0) {
        unsigned cnt = s_cnt < CBUF ? s_cnt : CBUF;
        s_n = cnt;
        s_base = atomicAdd(ccnt, cnt);
    }
    __syncthreads();
    const unsigned base = s_base, nn = s_n;
    for (unsigned j = threadIdx.x; j < nn; j += THREADS) {
        unsigned d = base + j;
        if (d < cap) { cval[d] = sv[j]; cidx[d] = si[j]; }
    }
}

// K3: level-3 histogram (key bits 7:0) of candidates matching level-2 bucket.
__global__ void __launch_bounds__(THREADS) k_hist8c(
    const float* __restrict__ cval, const unsigned* __restrict__ ccnt, unsigned cap,
    const unsigned* __restrict__ h12, const unsigned* __restrict__ h12b,
    unsigned* __restrict__ h8c, long long k0)
{
    __shared__ unsigned lh[256];
    unsigned b1, b2; long long k1, k2;
    block_select(h12, 16, k0, &b1, &k1);
    block_select(h12b, 16, k1, &b2, &k2);
    lh[threadIdx.x] = 0;
    __syncthreads();
    unsigned n = *ccnt; if (n > cap) n = cap;
    const unsigned stride = gridDim.x * THREADS;
    for (unsigned j = blockIdx.x * THREADS + threadIdx.x; j < n; j += stride) {
        unsigned k = f2key(cval[j]);
        if (((k >> 8) & 0xFFFu) == b2) atomicAdd(&lh[k & 0xFFu], 1u);
    }
    __syncthreads();
    unsigned s = lh[threadIdx.x];
    if (s) atomicAdd(&h8c[threadIdx.x], s);
}

// K4: derive exact kth, write scalar, fix up candidate positions of x_saved.
__global__ void __launch_bounds__(THREADS) k_finalize(
    const float* __restrict__ cval, const unsigned* __restrict__ cidx,
    const unsigned* __restrict__ ccnt, unsigned cap,
    float* __restrict__ outs_scalar, float* __restrict__ kth_out,
    const unsigned* __restrict__ h12, const unsigned* __restrict__ h12b,
    const unsigned* __restrict__ h8c, long long k0)
{
    unsigned b1, b2, b3; long long k1, k2, k3;
    block_select(h12, 16, k0, &b1, &k1);
    block_select(h12b, 16, k1, &b2, &k2);
    block_select(h8c, 1, k2, &b3, &k3);
    const unsigned kthkey = (b1 << 20) | (b2 << 8) | b3;
    const float kth = key2f(kthkey);
    if (blockIdx.x == 0 && threadIdx.x == 0) *kth_out = kth;
    unsigned n = *ccnt; if (n > cap) n = cap;
    const unsigned stride = gridDim.x * THREADS;
    for (unsigned j = blockIdx.x * THREADS + threadIdx.x; j < n; j += stride) {
        float v = cval[j];
        unsigned k = f2key(v);
        outs_scalar[cidx[j]] = (k > kthkey) ? v : -10.0f;
    }
}

// ======================= FALLBACK PATH (R1, proven) ========================

__global__ void __launch_bounds__(THREADS) k_gelu_hist8(
    const float4* __restrict__ x, float4* __restrict__ out,
    unsigned* __restrict__ hist8, long long n4)
{
    __shared__ unsigned lh[256 * 4];
    for (int i = threadIdx.x; i < 256 * 4; i += THREADS) lh[i] = 0;
    __syncthreads();
    const int c = threadIdx.x & 3;
    const long long stride = (long long)gridDim.x * THREADS;
    for (long long i = (long long)blockIdx.x * THREADS + threadIdx.x; i < n4; i += stride) {
        float4 v = x[i];
        float4 g;
        g.x = gelu_erf(v.x);
        g.y = gelu_erf(v.y);
        g.z = gelu_erf(v.z);
        g.w = gelu_erf(v.w);
        out[i] = g;
        atomicAdd(&lh[((f2key(v.x) >> 24) << 2) + c], 1u);
        atomicAdd(&lh[((f2key(v.y) >> 24) << 2) + c], 1u);
        atomicAdd(&lh[((f2key(v.z) >> 24) << 2) + c], 1u);
        atomicAdd(&lh[((f2key(v.w) >> 24) << 2) + c], 1u);
    }
    __syncthreads();
    const int t = threadIdx.x;
    unsigned s = lh[t * 4] + lh[t * 4 + 1] + lh[t * 4 + 2] + lh[t * 4 + 3];
    if (s) atomicAdd(&hist8[t], s);
}

__global__ void __launch_bounds__(THREADS) k_hist12(
    const float4* __restrict__ x, long long n4, long long k0,
    const unsigned* __restrict__ h8, const unsigned* __restrict__ h12a,
    unsigned* __restrict__ hist_out, int stage)
{
    __shared__ unsigned lh[4096];
    unsigned b1; long long k1;
    block_select(h8, 1, k0, &b1, &k1);
    unsigned matchval = b1;
    int matchshift = 24;
    if (stage == 1) {
        unsigned b2; long long k2;
        block_select(h12a, 16, k1, &b2, &k2);
        matchval = (b1 << 12) | b2;
        matchshift = 12;
    }
    for (int i = threadIdx.x; i < 4096; i += THREADS) lh[i] = 0;
    __syncthreads();
    const int binshift = matchshift - 12;
    const long long stride = (long long)gridDim.x * THREADS;
    for (long long i = (long long)blockIdx.x * THREADS + threadIdx.x; i < n4; i += stride) {
        float4 v = x[i];
        unsigned k;
        k = f2key(v.x); if ((k >> matchshift) == matchval) atomicAdd(&lh[(k >> binshift) & 0xFFFu], 1u);
        k = f2key(v.y); if ((k >> matchshift) == matchval) atomicAdd(&lh[(k >> binshift) & 0xFFFu], 1u);
        k = f2key(v.z); if ((k >> matchshift) == matchval) atomicAdd(&lh[(k >> binshift) & 0xFFFu], 1u);
        k = f2key(v.w); if ((k >> matchshift) == matchval) atomicAdd(&lh[(k >> binshift) & 0xFFFu], 1u);
    }
    __syncthreads();
    for (int i = threadIdx.x; i < 4096; i += THREADS) {
        unsigned s = lh[i];
        if (s) atomicAdd(&hist_out[i], s);
    }
}

__global__ void __launch_bounds__(THREADS) k_xsaved(
    const float4* __restrict__ x, float4* __restrict__ out, float* __restrict__ kth_out,
    const unsigned* __restrict__ h8, const unsigned* __restrict__ h12a,
    const unsigned* __restrict__ h12b, long long k0, long long n4)
{
    unsigned b1, b2, b3; long long k1, k2, k3;
    block_select(h8, 1, k0, &b1, &k1);
    block_select(h12a, 16, k1, &b2, &k2);
    block_select(h12b, 16, k2, &b3, &k3);
    const unsigned key = (b1 << 24) | (b2 << 12) | b3;
    const float kth = key2f(key);
    if (blockIdx.x == 0 && threadIdx.x == 0) *kth_out = kth;
    const long long stride = (long long)gridDim.x * THREADS;
    for (long long i = (long long)blockIdx.x * THREADS + threadIdx.x; i < n4; i += stride) {
        float4 v = x[i];
        float4 r;
        r.x = v.x > kth ? v.x : -10.0f;
        r.y = v.y > kth ? v.y : -10.0f;
        r.z = v.z > kth ? v.z : -10.0f;
        r.w = v.w > kth ? v.w : -10.0f;
        out[i] = r;
    }
}

// ===========================================================================

extern "C" void kernel_launch(void* const* d_in, const int* in_sizes, int n_in,
                              void* d_out, int out_size, void* d_ws, size_t ws_size,
                              hipStream_t stream) {
    (void)n_in; (void)out_size;
    const float* x = (const float*)d_in[0];
    float* out = (float*)d_out;
    const long long n = (long long)in_sizes[0];         // 33,554,432
    const long long n4 = n / 4;
    const long long k0 = (long long)((double)n * 0.9);  // matches Python int(n*0.9)

    float* gelu_out   = out;            // [0, n)
    float* xsaved_out = out + n;        // [n, 2n)
    float* kth_out    = out + 2 * n;    // [2n]

    // ws layout (fast path): h12[4096] | h12b[4096] | h8c[256] | cnt[1] | pad
    // then cval[cap] floats + cidx[cap] uints.
    const int HDR_U32 = 4096 + 4096 + 256 + 64;         // padded header
    const size_t hdr_bytes = (size_t)HDR_U32 * sizeof(unsigned);

    if (ws_size >= hdr_bytes + (size_t)16 * 1024 * 1024) {
        unsigned* h12  = (unsigned*)d_ws;
        unsigned* h12b = h12 + 4096;
        unsigned* h8c  = h12b + 4096;
        unsigned* ccnt = h8c + 256;
        unsigned cap = (unsigned)((ws_size - hdr_bytes) / 8);
        float*    cval = (float*)((char*)d_ws + hdr_bytes);
        unsigned* cidx = (unsigned*)(cval + cap);

        k_zero<<<(HDR_U32 + THREADS - 1) / THREADS, THREADS, 0, stream>>>((unsigned*)d_ws, HDR_U32);
        k_gelu_hist12<<<1024, THREADS, 0, stream>>>((const float4*)x, (float4*)gelu_out, h12, n4);
        k_saved_compact<<<1024, THREADS, 0, stream>>>((const float4*)x, (float4*)xsaved_out,
                                                      h12, h12b, cval, cidx, ccnt, cap, k0, n4);
        k_hist8c<<<256, THREADS, 0, stream>>>(cval, ccnt, cap, h12, h12b, h8c, k0);
        k_finalize<<<256, THREADS, 0, stream>>>(cval, cidx, ccnt, cap, xsaved_out, kth_out,
                                                h12, h12b, h8c, k0);
    } else {
        // Fallback: proven R1 4-pass path (needs only ~34 KB of ws).
        unsigned* h8   = (unsigned*)d_ws;
        unsigned* h12a = h8 + 256;
        unsigned* h12b = h12a + 4096;
        const int FB_U32 = 256 + 4096 + 4096;
        k_zero<<<(FB_U32 + THREADS - 1) / THREADS, THREADS, 0, stream>>>((unsigned*)d_ws, FB_U32);
        const int blocks = 2048;
        k_gelu_hist8<<<blocks, THREADS, 0, stream>>>((const float4*)x, (float4*)gelu_out, h8, n4);
        k_hist12<<<blocks, THREADS, 0, stream>>>((const float4*)x, n4, k0, h8, h12a, h12a, 0);
        k_hist12<<<blocks, THREADS, 0, stream>>>((const float4*)x, n4, k0, h8, h12a, h12b, 1);
        k_xsaved<<<blocks, THREADS, 0, stream>>>((const float4*)x, (float4*)xsaved_out, kth_out,
                                                 h8, h12a, h12b, k0, n4);
    }
}